// Round 16
// baseline (81.651 us; speedup 1.0000x reference)
//
#include <hip/hip_runtime.h>

typedef __attribute__((ext_vector_type(8))) _Float16 f16x8;
typedef __attribute__((ext_vector_type(4))) _Float16 f16x4;
typedef __attribute__((ext_vector_type(2))) __fp16 fp16v2;  // cvt_pkrtz result type
typedef __attribute__((ext_vector_type(4))) float f32x4;
typedef __attribute__((ext_vector_type(16))) float f32x16;

#define NB 16
#define MAXC 256
#define MAXT 4096
#define HID 512
#define NSRC 256

// Publish barrier: drains DMA (vmcnt) + LDS, then syncs (m97 structure).
#define BARV() asm volatile("s_waitcnt vmcnt(0) lgkmcnt(0)\n\ts_barrier" ::: "memory")
// WAR-only barrier: LDS reads retired before DMA overwrites the buffer.
#define BAR() asm volatile("s_waitcnt lgkmcnt(0)\n\ts_barrier" ::: "memory")

#define MFMA32(a, b, c) __builtin_amdgcn_mfma_f32_32x32x16_f16(a, b, c, 0, 0, 0)

typedef __attribute__((address_space(1))) const void gconst_void;
typedef __attribute__((address_space(3))) void lds_void;
// 16B-per-lane async global->LDS: LDS dest = wave-uniform base + lane*16;
// global src is per-lane (XOR swizzle folded into the source address).
#define GLOAD16(gp, lp) \
  __builtin_amdgcn_global_load_lds((gconst_void*)(gp), (lds_void*)(lp), 16, 0, 0)

// gelu(x) ~= x * sigmoid(1.5957691x + 0.0713548x^3)   (tanh-form, |err| ~3e-4)
__device__ __forceinline__ float gelu_fast(float x) {
  float p = x * x;
  float q = __builtin_fmaf(p, -0.10294336f, -2.30220778f);
  float e = __builtin_amdgcn_exp2f(x * q);
  return x * __builtin_amdgcn_rcpf(1.0f + e);
}

// fp32 (R x C) -> fp16 (C x R), one 32x32 tile, flat 256-thread block
__device__ __forceinline__ void transpose_cvt_tile(const float* src, _Float16* dst,
                                                   int R, int C, int cx, int ry,
                                                   int tid) {
  __shared__ float tile[32][33];
  int c0 = cx * 32, r0 = ry * 32;
  int tx = tid & 31, ty = tid >> 5;
  for (int i = ty; i < 32; i += 8)
    tile[i][tx] = src[(size_t)(r0 + i) * C + (c0 + tx)];
  __syncthreads();
  for (int i = ty; i < 32; i += 8)
    dst[(size_t)(c0 + i) * R + (r0 + tx)] = (_Float16)tile[tx][i];
}

// Fused prep: [0,4096) x-transpose tiles; [4096,5120) W_sess; [5120,5248) W2.
__global__ __launch_bounds__(256)
void prep_kernel(const float* __restrict__ x,
                 const int* __restrict__ seq_lens,
                 const int* __restrict__ chan_counts,
                 const float* __restrict__ W_sess,
                 const float* __restrict__ W2,
                 _Float16* __restrict__ xT,
                 _Float16* __restrict__ W1t,
                 _Float16* __restrict__ W2t) {
  int wg = blockIdx.x;
  int tid = threadIdx.x;

  if (wg >= 4096) {
    if (wg >= 5120) {  // W2: (HID x NSRC) -> (NSRC x HID)
      int idx = wg - 5120;
      transpose_cvt_tile(W2, W2t, HID, NSRC, idx & 7, idx >> 3, tid);
    } else {           // W_sess[z]: (MAXC x HID) -> (HID x MAXC)
      int idx = wg - 4096;
      int z = idx >> 7;
      transpose_cvt_tile(W_sess + (size_t)z * MAXC * HID,
                         W1t + (size_t)z * MAXC * HID,
                         MAXC, HID, idx & 15, (idx >> 4) & 7, tid);
    }
    return;
  }

  // x [b][c][t] fp32 -> xT [b][t][c] fp16, 64x64 tile
  int b = wg >> 8;
  int t0 = (wg & 63) * 64;
  int c0 = ((wg >> 6) & 3) * 64;
  int seqlen = seq_lens[b];
  if (t0 >= ((seqlen + 127) & ~127)) return;
  int wt = tid >> 5;           // 0..7: t-row group
  int c2 = (tid & 31) * 2;     // channel pair
  _Float16* op = xT + ((size_t)b * MAXT + t0) * MAXC + c0;

  if (c0 >= chan_counts[b]) {  // fully padded channel block: zeros, no read
    #pragma unroll
    for (int i = 0; i < 8; ++i) {
      fp16v2 z = {(_Float16)0.f, (_Float16)0.f};
      *(fp16v2*)(op + (size_t)(wt + i * 8) * MAXC + c2) = z;
    }
    return;
  }

  __shared__ float tile[64][65];
  int tx = tid & 63, ty = tid >> 6;
  const float* xp = x + ((size_t)b * MAXC + c0) * MAXT + t0;
  #pragma unroll
  for (int i = 0; i < 16; ++i) {
    int c = ty + i * 4;
    tile[c][tx] = xp[(size_t)c * MAXT + tx];
  }
  __syncthreads();
  #pragma unroll
  for (int i = 0; i < 8; ++i) {
    int tl = wt + i * 8;
    fp16v2 p = __builtin_amdgcn_cvt_pkrtz(tile[c2][tl], tile[c2 + 1][tl]);
    *(fp16v2*)(op + (size_t)tl * MAXC + c2) = p;
  }
}

// LDS layout: row r, 16B granule slot s holds global granule (s&~7)|((s&7)^(r&7))
// -- XOR swizzle folded into the global_load_lds SOURCE address.
// 32x32x16 MFMA fragments: lane l -> row/col = l&31, k-granule parity = l>>5;
// granule index for k-step ks is ks*2 + (l>>5). D: col=lane&31,
// row=(reg&3)+8*(reg>>2)+4*(lane>>5)  [HW-verified m74/m101].

// ===== GEMM1: h_t[b][t][h] = gelu(W1t[sid] @ xT[b]^T + b1).
// Tile [256 h][128 t], 512 threads / 8 waves, K=256 in 4 steps. =====
__global__ __launch_bounds__(512, 2)
void gemm1_kernel(const _Float16* __restrict__ xT,   // [NB][MAXT][MAXC]
                  const int* __restrict__ sess_ids,
                  const int* __restrict__ seq_lens,
                  const _Float16* __restrict__ W1t,   // [8][HID][MAXC]
                  const float* __restrict__ b_sess,   // [8][HID]
                  _Float16* __restrict__ h_t) {       // [NB][MAXT][HID]
  int wg = blockIdx.x;
  int nt = wg & 31;
  int mt = (wg >> 5) & 1;
  int b = wg >> 6;
  int tb0 = nt * 128, h0 = mt * 256;
  int seqlen = seq_lens[b];
  if (tb0 >= seqlen) return;  // h_t left unwritten; gemm2 never reads these tiles
  int sid = sess_ids[b];

  __shared__ _Float16 As[256 * 64];  // 32 KB [h-row][c granule slots]
  __shared__ _Float16 Bs[128 * 64];  // 16 KB [t-row][c granule slots]

  int tid = threadIdx.x;
  int lane = tid & 63, w = tid >> 6;     // 8 waves
  int wr = w >> 1, wc = w & 1;           // wr 0..3 (64h), wc 0..1 (64t)
  int lm = lane & 31;                    // MFMA row/col
  int kl = lane >> 5;                    // k-half
  int rsub = lane >> 3;
  int swb = ((lane & 7) ^ rsub) * 16;

  f32x16 acc[2][2];
  #pragma unroll
  for (int mi = 0; mi < 2; ++mi)
    #pragma unroll
    for (int q = 0; q < 4; ++q) {
      f32x4 bv = *(const f32x4*)(b_sess + sid * HID + h0 + wr * 64 + mi * 32 + q * 8 + kl * 4);
      #pragma unroll
      for (int ni = 0; ni < 2; ++ni)
        #pragma unroll
        for (int r = 0; r < 4; ++r) acc[mi][ni][q * 4 + r] = bv[r];
    }

  const char* gA = (const char*)(W1t + (size_t)sid * HID * MAXC + (size_t)h0 * MAXC)
                   + (size_t)(w * 32 + rsub) * 512 + swb;
  const char* gB = (const char*)(xT + ((size_t)b * MAXT + tb0) * MAXC)
                   + (size_t)(w * 16 + rsub) * 512 + swb;
  char* lA = (char*)As + w * 4096;   // wave covers A rows w*32..+31 (4 KB)
  char* lB = (char*)Bs + w * 2048;   // wave covers B rows w*16..+15 (2 KB)

#define STAGE1(kc)                                                        \
  {                                                                       \
    _Pragma("unroll")                                                     \
    for (int j = 0; j < 4; ++j)                                           \
      GLOAD16(gA + (size_t)(kc)*128 + (size_t)j * 8 * 512, lA + j * 1024); \
    _Pragma("unroll")                                                     \
    for (int j = 0; j < 2; ++j)                                           \
      GLOAD16(gB + (size_t)(kc)*128 + (size_t)j * 8 * 512, lB + j * 1024); \
  }

  STAGE1(0);
  BARV();

  #pragma unroll 1
  for (int kc = 0; kc < 4; ++kc) {
    #pragma unroll
    for (int ks = 0; ks < 4; ++ks) {
      int g = ks * 2 + kl;  // k-granule for this lane
      f16x8 af[2], bf[2];
      #pragma unroll
      for (int mi = 0; mi < 2; ++mi) {
        int row = wr * 64 + mi * 32 + lm;
        af[mi] = *(const f16x8*)(&As[row * 64 + ((g ^ (row & 7)) * 8)]);
      }
      #pragma unroll
      for (int ni = 0; ni < 2; ++ni) {
        int t = wc * 64 + ni * 32 + lm;
        bf[ni] = *(const f16x8*)(&Bs[t * 64 + ((g ^ (t & 7)) * 8)]);
      }
      __builtin_amdgcn_s_setprio(1);
      #pragma unroll
      for (int mi = 0; mi < 2; ++mi)
        #pragma unroll
        for (int ni = 0; ni < 2; ++ni)
          acc[mi][ni] = MFMA32(af[mi], bf[ni], acc[mi][ni]);
      __builtin_amdgcn_s_setprio(0);
    }
    if (kc < 3) {
      BAR();           // readers done (WAR)
      STAGE1(kc + 1);
      BARV();          // staged tile visible
    }
  }

  // ---- epilogue: gelu -> h_t fp16 [b][t][h] ----
  _Float16* hp = h_t + (size_t)b * MAXT * HID;
  #pragma unroll
  for (int mi = 0; mi < 2; ++mi)
    #pragma unroll
    for (int ni = 0; ni < 2; ++ni) {
      int t = tb0 + wc * 64 + ni * 32 + lm;
      #pragma unroll
      for (int q = 0; q < 4; ++q) {
        int h = h0 + wr * 64 + mi * 32 + q * 8 + kl * 4;
        f16x4 gv;
        #pragma unroll
        for (int r = 0; r < 4; ++r) gv[r] = (_Float16)gelu_fast(acc[mi][ni][q * 4 + r]);
        *(f16x4*)(hp + (size_t)t * HID + h) = gv;
      }
    }
}

// ===== GEMM2: out[b][s][t] = (W2t @ h_t[b]^T + b2) * tmask.
// Tile [256 s = full NSRC][128 t], 512 threads / 8 waves, K=512 in 8 steps. =====
__global__ __launch_bounds__(512, 2)
void gemm2_kernel(const int* __restrict__ seq_lens,
                  const _Float16* __restrict__ W2t,   // [NSRC][HID]
                  const float* __restrict__ b2,       // [NSRC]
                  const _Float16* __restrict__ h_t,   // [NB][MAXT][HID]
                  float* __restrict__ out) {
  int wg = blockIdx.x;
  int nt = wg & 31;
  int b = wg >> 5;
  int tb0 = nt * 128;
  int seqlen = seq_lens[b];
  int tid = threadIdx.x;

  if (tb0 >= seqlen) {  // fully masked: write zeros, never touch h_t
    int sr = tid >> 1, tq = (tid & 1) * 64;
    float* po = out + ((size_t)b * NSRC + sr) * MAXT + tb0 + tq;
    f32x4 z = {0.f, 0.f, 0.f, 0.f};
    #pragma unroll
    for (int i = 0; i < 16; ++i) *(f32x4*)(po + i * 4) = z;
    return;
  }

  __shared__ _Float16 As[256 * 64];  // 32 KB [s-row][h granule slots]
  __shared__ _Float16 Bs[128 * 64];  // 16 KB [t-row][h granule slots]

  int lane = tid & 63, w = tid >> 6;     // 8 waves
  int wr = w >> 1, wc = w & 1;           // wr 0..3 (64s), wc 0..1 (64t)
  int lm = lane & 31;
  int kl = lane >> 5;
  int rsub = lane >> 3;
  int swb = ((lane & 7) ^ rsub) * 16;

  f32x16 acc[2][2];
  #pragma unroll
  for (int mi = 0; mi < 2; ++mi)
    #pragma unroll
    for (int q = 0; q < 4; ++q) {
      f32x4 bv = *(const f32x4*)(b2 + wr * 64 + mi * 32 + q * 8 + kl * 4);
      #pragma unroll
      for (int ni = 0; ni < 2; ++ni)
        #pragma unroll
        for (int r = 0; r < 4; ++r) acc[mi][ni][q * 4 + r] = bv[r];
    }

  const char* gA = (const char*)W2t + (size_t)(w * 32 + rsub) * 1024 + swb;
  const char* gB = (const char*)(h_t + ((size_t)b * MAXT + tb0) * HID)
                   + (size_t)(w * 16 + rsub) * 1024 + swb;
  char* lA = (char*)As + w * 4096;   // wave covers A rows w*32..+31
  char* lB = (char*)Bs + w * 2048;   // wave covers B rows w*16..+15

#define STAGE2(kc)                                                         \
  {                                                                        \
    _Pragma("unroll")                                                      \
    for (int j = 0; j < 4; ++j)                                            \
      GLOAD16(gA + (size_t)(kc)*128 + (size_t)j * 8 * 1024, lA + j * 1024); \
    _Pragma("unroll")                                                      \
    for (int j = 0; j < 2; ++j)                                            \
      GLOAD16(gB + (size_t)(kc)*128 + (size_t)j * 8 * 1024, lB + j * 1024); \
  }

  STAGE2(0);
  BARV();

  #pragma unroll 1
  for (int kc = 0; kc < 8; ++kc) {
    #pragma unroll
    for (int ks = 0; ks < 4; ++ks) {
      int g = ks * 2 + kl;
      f16x8 af[2], bf[2];
      #pragma unroll
      for (int mi = 0; mi < 2; ++mi) {
        int row = wr * 64 + mi * 32 + lm;
        af[mi] = *(const f16x8*)(&As[row * 64 + ((g ^ (row & 7)) * 8)]);
      }
      #pragma unroll
      for (int ni = 0; ni < 2; ++ni) {
        int t = wc * 64 + ni * 32 + lm;
        bf[ni] = *(const f16x8*)(&Bs[t * 64 + ((g ^ (t & 7)) * 8)]);
      }
      __builtin_amdgcn_s_setprio(1);
      #pragma unroll
      for (int mi = 0; mi < 2; ++mi)
        #pragma unroll
        for (int ni = 0; ni < 2; ++ni)
          acc[mi][ni] = MFMA32(af[mi], bf[ni], acc[mi][ni]);
      __builtin_amdgcn_s_setprio(0);
    }
    if (kc < 7) {
      BAR();
      STAGE2(kc + 1);
      BARV();
    }
  }

  // ---- epilogue: time mask + fp32 store ----
  #pragma unroll
  for (int mi = 0; mi < 2; ++mi)
    #pragma unroll
    for (int ni = 0; ni < 2; ++ni) {
      int t = tb0 + wc * 64 + ni * 32 + lm;
      float m = (t < seqlen) ? 1.0f : 0.0f;
      #pragma unroll
      for (int q = 0; q < 4; ++q) {
        int s = wr * 64 + mi * 32 + q * 8 + kl * 4;
        #pragma unroll
        for (int r = 0; r < 4; ++r)
          out[((size_t)b * NSRC + s + r) * MAXT + t] = acc[mi][ni][q * 4 + r] * m;
      }
    }
}

extern "C" void kernel_launch(void* const* d_in, const int* in_sizes, int n_in,
                              void* d_out, int out_size, void* d_ws, size_t ws_size,
                              hipStream_t stream) {
  const float* x      = (const float*)d_in[0];
  const int* sess     = (const int*)d_in[1];
  const int* ccnt     = (const int*)d_in[2];
  const int* seq      = (const int*)d_in[3];
  const float* W_sess = (const float*)d_in[4];
  const float* b_sess = (const float*)d_in[5];
  const float* W2     = (const float*)d_in[6];
  const float* b2     = (const float*)d_in[7];
  float* out = (float*)d_out;

  char* wp = (char*)d_ws;
  _Float16* W1t = (_Float16*)wp;                     wp += (size_t)8 * HID * MAXC * 2;   // 2 MB
  _Float16* W2t = (_Float16*)wp;                     wp += (size_t)NSRC * HID * 2;       // 256 KB
  _Float16* h_t = (_Float16*)wp;                     wp += (size_t)NB * MAXT * HID * 2;  // 64 MB
  _Float16* xT  = (_Float16*)wp;                                                          // 32 MB

  prep_kernel<<<dim3(4096 + 1024 + 128), dim3(256), 0, stream>>>(
      x, seq, ccnt, W_sess, W2, xT, W1t, W2t);
  gemm1_kernel<<<dim3(NB * 2 * 32), dim3(512), 0, stream>>>(xT, sess, seq, W1t, b_sess, h_t);
  gemm2_kernel<<<dim3(NB * 32), dim3(512), 0, stream>>>(seq, W2t, b2, h_t, out);
}

// Round 17
// 75.356 us; speedup vs baseline: 1.0835x; 1.0835x over previous
//
#include <hip/hip_runtime.h>

typedef __attribute__((ext_vector_type(8))) _Float16 f16x8;
typedef __attribute__((ext_vector_type(4))) _Float16 f16x4;
typedef __attribute__((ext_vector_type(2))) __fp16 fp16v2;  // cvt_pkrtz result type
typedef __attribute__((ext_vector_type(4))) float f32x4;

#define NB 16
#define MAXC 256
#define MAXT 4096
#define HID 512
#define NSRC 256

// Publish barrier: drains DMA (vmcnt) + LDS, then syncs (m97 structure).
#define BARV() asm volatile("s_waitcnt vmcnt(0) lgkmcnt(0)\n\ts_barrier" ::: "memory")
// WAR-only barrier: LDS reads retired before DMA overwrites the buffer.
#define BAR() asm volatile("s_waitcnt lgkmcnt(0)\n\ts_barrier" ::: "memory")

#define MFMA(a, b, c) __builtin_amdgcn_mfma_f32_16x16x32_f16(a, b, c, 0, 0, 0)

typedef __attribute__((address_space(1))) const void gconst_void;
typedef __attribute__((address_space(3))) void lds_void;
// 16B-per-lane async global->LDS: LDS dest = wave-uniform base + lane*16;
// global src is per-lane (XOR swizzle folded into the source address).
#define GLOAD16(gp, lp) \
  __builtin_amdgcn_global_load_lds((gconst_void*)(gp), (lds_void*)(lp), 16, 0, 0)

// gelu(x) ~= x * sigmoid(1.5957691x + 0.0713548x^3)   (tanh-form, |err| ~3e-4)
__device__ __forceinline__ float gelu_fast(float x) {
  float p = x * x;
  float q = __builtin_fmaf(p, -0.10294336f, -2.30220778f);
  float e = __builtin_amdgcn_exp2f(x * q);
  return x * __builtin_amdgcn_rcpf(1.0f + e);
}

// fp32 (R x C) -> fp16 (C x R), one 32x32 tile, flat 256-thread block
__device__ __forceinline__ void transpose_cvt_tile(const float* src, _Float16* dst,
                                                   int R, int C, int cx, int ry,
                                                   int tid) {
  __shared__ float tile[32][33];
  int c0 = cx * 32, r0 = ry * 32;
  int tx = tid & 31, ty = tid >> 5;
  for (int i = ty; i < 32; i += 8)
    tile[i][tx] = src[(size_t)(r0 + i) * C + (c0 + tx)];
  __syncthreads();
  for (int i = ty; i < 32; i += 8)
    dst[(size_t)(c0 + i) * R + (r0 + tx)] = (_Float16)tile[tx][i];
}

// Fused prep: [0,4096) x-transpose tiles; [4096,5120) W_sess; [5120,5248) W2.
__global__ __launch_bounds__(256)
void prep_kernel(const float* __restrict__ x,
                 const int* __restrict__ seq_lens,
                 const int* __restrict__ chan_counts,
                 const float* __restrict__ W_sess,
                 const float* __restrict__ W2,
                 _Float16* __restrict__ xT,
                 _Float16* __restrict__ W1t,
                 _Float16* __restrict__ W2t) {
  int wg = blockIdx.x;
  int tid = threadIdx.x;

  if (wg >= 4096) {
    if (wg >= 5120) {  // W2: (HID x NSRC) -> (NSRC x HID)
      int idx = wg - 5120;
      transpose_cvt_tile(W2, W2t, HID, NSRC, idx & 7, idx >> 3, tid);
    } else {           // W_sess[z]: (MAXC x HID) -> (HID x MAXC)
      int idx = wg - 4096;
      int z = idx >> 7;
      transpose_cvt_tile(W_sess + (size_t)z * MAXC * HID,
                         W1t + (size_t)z * MAXC * HID,
                         MAXC, HID, idx & 15, (idx >> 4) & 7, tid);
    }
    return;
  }

  // x [b][c][t] fp32 -> xT [b][t][c] fp16, 64x64 tile
  int b = wg >> 8;
  int t0 = (wg & 63) * 64;
  int c0 = ((wg >> 6) & 3) * 64;
  int seqlen = seq_lens[b];
  if (t0 >= ((seqlen + 127) & ~127)) return;
  int wt = tid >> 5;           // 0..7: t-row group
  int c2 = (tid & 31) * 2;     // channel pair
  _Float16* op = xT + ((size_t)b * MAXT + t0) * MAXC + c0;

  if (c0 >= chan_counts[b]) {  // fully padded channel block: zeros, no read
    #pragma unroll
    for (int i = 0; i < 8; ++i) {
      fp16v2 z = {(_Float16)0.f, (_Float16)0.f};
      *(fp16v2*)(op + (size_t)(wt + i * 8) * MAXC + c2) = z;
    }
    return;
  }

  __shared__ float tile[64][65];
  int tx = tid & 63, ty = tid >> 6;
  const float* xp = x + ((size_t)b * MAXC + c0) * MAXT + t0;
  #pragma unroll
  for (int i = 0; i < 16; ++i) {
    int c = ty + i * 4;
    tile[c][tx] = xp[(size_t)c * MAXT + tx];
  }
  __syncthreads();
  #pragma unroll
  for (int i = 0; i < 8; ++i) {
    int tl = wt + i * 8;
    fp16v2 p = __builtin_amdgcn_cvt_pkrtz(tile[c2][tl], tile[c2 + 1][tl]);
    *(fp16v2*)(op + (size_t)tl * MAXC + c2) = p;
  }
}

// LDS layout: row r, 16B slot s holds global chunk (s&~7)|((s&7)^(r&7)) --
// XOR swizzle folded into the global_load_lds SOURCE address.

// ===== GEMM1: h_t[b][t][h] = gelu(W1t[sid] @ xT[b]^T + b1).
// Tile [256 h][128 t], 512 threads / 8 waves, K=256 in 4 steps.
// XCD-swizzled grid: logical id L = (pid%8)*128 + pid/8; mt = lowest bit so
// the two WGs sharing an xT B-panel are XCD-adjacent.
__global__ __launch_bounds__(512, 2)
void gemm1_kernel(const _Float16* __restrict__ xT,   // [NB][MAXT][MAXC]
                  const int* __restrict__ sess_ids,
                  const int* __restrict__ seq_lens,
                  const _Float16* __restrict__ W1t,   // [8][HID][MAXC]
                  const float* __restrict__ b_sess,   // [8][HID]
                  _Float16* __restrict__ h_t) {       // [NB][MAXT][HID]
  int pid = blockIdx.x;
  int L = (pid & 7) * 128 + (pid >> 3);   // bijective (1024 % 8 == 0)
  int mt = L & 1;
  int nt = (L >> 1) & 31;
  int b = L >> 6;
  int tb0 = nt * 128, h0 = mt * 256;
  int seqlen = seq_lens[b];
  if (tb0 >= seqlen) return;  // h_t left unwritten; gemm2 never reads these tiles
  int sid = sess_ids[b];

  __shared__ _Float16 As[256 * 64];  // 32 KB [h-row][c slots]
  __shared__ _Float16 Bs[128 * 64];  // 16 KB [t-row][c slots]

  int tid = threadIdx.x;
  int lane = tid & 63, w = tid >> 6;     // 8 waves
  int wr = w >> 1, wc = w & 1;           // wr 0..3 (64h), wc 0..1 (64t)
  int lg = lane >> 4, lr = lane & 15;

  f32x4 acc[4][4];
  #pragma unroll
  for (int mi = 0; mi < 4; ++mi) {
    f32x4 bv = *(const f32x4*)(b_sess + sid * HID + h0 + wr * 64 + mi * 16 + lg * 4);
    #pragma unroll
    for (int ni = 0; ni < 4; ++ni) acc[mi][ni] = bv;
  }

  int rsub = lane >> 3;                  // row within 8-row group
  int swb = ((lane & 7) ^ rsub) * 16;    // swizzled byte offset in 128B slice
  const char* gA = (const char*)(W1t + (size_t)sid * HID * MAXC + (size_t)h0 * MAXC)
                   + (size_t)(w * 32 + rsub) * 512 + swb;
  const char* gB = (const char*)(xT + ((size_t)b * MAXT + tb0) * MAXC)
                   + (size_t)(w * 16 + rsub) * 512 + swb;
  char* lA = (char*)As + w * 4096;   // wave covers A rows w*32..+31 (4 KB)
  char* lB = (char*)Bs + w * 2048;   // wave covers B rows w*16..+15 (2 KB)

#define STAGE1(kc)                                                        \
  {                                                                       \
    _Pragma("unroll")                                                     \
    for (int j = 0; j < 4; ++j)                                           \
      GLOAD16(gA + (size_t)(kc)*128 + (size_t)j * 8 * 512, lA + j * 1024); \
    _Pragma("unroll")                                                     \
    for (int j = 0; j < 2; ++j)                                           \
      GLOAD16(gB + (size_t)(kc)*128 + (size_t)j * 8 * 512, lB + j * 1024); \
  }

  STAGE1(0);
  BARV();

  #pragma unroll 1
  for (int kc = 0; kc < 4; ++kc) {
    #pragma unroll
    for (int slot = 0; slot < 2; ++slot) {
      f16x8 af[4], bf[4];
      #pragma unroll
      for (int mi = 0; mi < 4; ++mi) {
        int row = wr * 64 + mi * 16 + lr;
        af[mi] = *(const f16x8*)(&As[row * 64 + (((slot * 4 + lg) ^ (row & 7)) * 8)]);
      }
      #pragma unroll
      for (int ni = 0; ni < 4; ++ni) {
        int t = wc * 64 + ni * 16 + lr;
        bf[ni] = *(const f16x8*)(&Bs[t * 64 + (((slot * 4 + lg) ^ (t & 7)) * 8)]);
      }
      __builtin_amdgcn_s_setprio(1);
      #pragma unroll
      for (int mi = 0; mi < 4; ++mi)
        #pragma unroll
        for (int ni = 0; ni < 4; ++ni)
          acc[mi][ni] = MFMA(af[mi], bf[ni], acc[mi][ni]);
      __builtin_amdgcn_s_setprio(0);
    }
    if (kc < 3) {
      BAR();           // readers done (WAR)
      STAGE1(kc + 1);
      BARV();          // staged tile visible
    }
  }

  // ---- epilogue: gelu -> h_t fp16 [b][t][h] ----
  _Float16* hp = h_t + (size_t)b * MAXT * HID;
  #pragma unroll
  for (int mi = 0; mi < 4; ++mi) {
    int h = h0 + wr * 64 + mi * 16 + lg * 4;
    #pragma unroll
    for (int ni = 0; ni < 4; ++ni) {
      int t = tb0 + wc * 64 + ni * 16 + lr;
      f16x4 g;
      #pragma unroll
      for (int r = 0; r < 4; ++r) g[r] = (_Float16)gelu_fast(acc[mi][ni][r]);
      *(f16x4*)(hp + (size_t)t * HID + h) = g;
    }
  }
}

// ===== GEMM2: out[b][s][t] = (W2t @ h_t[b]^T + b2) * tmask, tile 128x128,
// K=512 in 8 steps.  XCD-swizzled grid; mt = lowest bit so the two WGs
// sharing an h_t B-panel are XCD-adjacent.
__global__ __launch_bounds__(256, 4)
void gemm2_kernel(const int* __restrict__ seq_lens,
                  const _Float16* __restrict__ W2t,   // [NSRC][HID]
                  const float* __restrict__ b2,       // [NSRC]
                  const _Float16* __restrict__ h_t,   // [NB][MAXT][HID]
                  float* __restrict__ out) {
  int pid = blockIdx.x;
  int L = (pid & 7) * 128 + (pid >> 3);   // bijective (1024 % 8 == 0)
  int mt = L & 1;
  int nt = (L >> 1) & 31;
  int b = L >> 6;
  int tb0 = nt * 128, s0 = mt * 128;
  int seqlen = seq_lens[b];
  int tid = threadIdx.x;

  if (tb0 >= seqlen) {  // fully masked: write zeros, never touch h_t
    int sr = tid >> 1, tq = (tid & 1) * 64;
    float* po = out + ((size_t)b * NSRC + s0 + sr) * MAXT + tb0 + tq;
    f32x4 z = {0.f, 0.f, 0.f, 0.f};
    #pragma unroll
    for (int i = 0; i < 16; ++i) *(f32x4*)(po + i * 4) = z;
    return;
  }

  __shared__ _Float16 As[128 * 64];  // [s-row][h-chunk slots]
  __shared__ _Float16 Bs[128 * 64];  // [t-row][h-chunk slots]

  int lane = tid & 63, w = tid >> 6;
  int wr = w >> 1, wc = w & 1;
  int lg = lane >> 4, lr = lane & 15;

  f32x4 acc[4][4];
  #pragma unroll
  for (int mi = 0; mi < 4; ++mi) {
    f32x4 bv = *(const f32x4*)(b2 + s0 + wr * 64 + mi * 16 + lg * 4);
    #pragma unroll
    for (int ni = 0; ni < 4; ++ni) acc[mi][ni] = bv;
  }

  int rsub = lane >> 3;
  int swb = ((lane & 7) ^ rsub) * 16;
  const char* gA = (const char*)(W2t + (size_t)s0 * HID)
                   + (size_t)(w * 32 + rsub) * 1024 + swb;
  const char* gB = (const char*)(h_t + ((size_t)b * MAXT + tb0) * HID)
                   + (size_t)(w * 32 + rsub) * 1024 + swb;
  char* lA = (char*)As + w * 4096;
  char* lB = (char*)Bs + w * 4096;

#define STAGE2(kc)                                                    \
  _Pragma("unroll")                                                   \
  for (int j = 0; j < 4; ++j) {                                       \
    GLOAD16(gA + (size_t)(kc)*128 + (size_t)j * 8 * 1024, lA + j * 1024); \
    GLOAD16(gB + (size_t)(kc)*128 + (size_t)j * 8 * 1024, lB + j * 1024); \
  }

  STAGE2(0);
  BARV();

  #pragma unroll 1
  for (int kc = 0; kc < 8; ++kc) {
    #pragma unroll
    for (int slot = 0; slot < 2; ++slot) {
      f16x8 af[4], bf[4];
      #pragma unroll
      for (int mi = 0; mi < 4; ++mi) {
        int row = wr * 64 + mi * 16 + lr;
        af[mi] = *(const f16x8*)(&As[row * 64 + (((slot * 4 + lg) ^ (row & 7)) * 8)]);
      }
      #pragma unroll
      for (int ni = 0; ni < 4; ++ni) {
        int t = wc * 64 + ni * 16 + lr;
        bf[ni] = *(const f16x8*)(&Bs[t * 64 + (((slot * 4 + lg) ^ (t & 7)) * 8)]);
      }
      __builtin_amdgcn_s_setprio(1);
      #pragma unroll
      for (int mi = 0; mi < 4; ++mi)
        #pragma unroll
        for (int ni = 0; ni < 4; ++ni)
          acc[mi][ni] = MFMA(af[mi], bf[ni], acc[mi][ni]);
      __builtin_amdgcn_s_setprio(0);
    }
    if (kc < 7) {
      BAR();
      STAGE2(kc + 1);
      BARV();
    }
  }

  // ---- epilogue: time mask + fp32 store ----
  #pragma unroll
  for (int mi = 0; mi < 4; ++mi) {
    int s = s0 + wr * 64 + mi * 16 + lg * 4;
    #pragma unroll
    for (int ni = 0; ni < 4; ++ni) {
      int t = tb0 + wc * 64 + ni * 16 + lr;
      float m = (t < seqlen) ? 1.0f : 0.0f;
      #pragma unroll
      for (int r = 0; r < 4; ++r)
        out[((size_t)b * NSRC + s + r) * MAXT + t] = acc[mi][ni][r] * m;
    }
  }
}

extern "C" void kernel_launch(void* const* d_in, const int* in_sizes, int n_in,
                              void* d_out, int out_size, void* d_ws, size_t ws_size,
                              hipStream_t stream) {
  const float* x      = (const float*)d_in[0];
  const int* sess     = (const int*)d_in[1];
  const int* ccnt     = (const int*)d_in[2];
  const int* seq      = (const int*)d_in[3];
  const float* W_sess = (const float*)d_in[4];
  const float* b_sess = (const float*)d_in[5];
  const float* W2     = (const float*)d_in[6];
  const float* b2     = (const float*)d_in[7];
  float* out = (float*)d_out;

  char* wp = (char*)d_ws;
  _Float16* W1t = (_Float16*)wp;                     wp += (size_t)8 * HID * MAXC * 2;   // 2 MB
  _Float16* W2t = (_Float16*)wp;                     wp += (size_t)NSRC * HID * 2;       // 256 KB
  _Float16* h_t = (_Float16*)wp;                     wp += (size_t)NB * MAXT * HID * 2;  // 64 MB
  _Float16* xT  = (_Float16*)wp;                                                          // 32 MB

  prep_kernel<<<dim3(4096 + 1024 + 128), dim3(256), 0, stream>>>(
      x, seq, ccnt, W_sess, W2, xT, W1t, W2t);
  gemm1_kernel<<<dim3(NB * 2 * 32), dim3(512), 0, stream>>>(xT, sess, seq, W1t, b_sess, h_t);
  gemm2_kernel<<<dim3(NB * 2 * 32), dim3(256), 0, stream>>>(seq, W2t, b2, h_t, out);
}